// Round 2
// baseline (336.641 us; speedup 1.0000x reference)
//
#include <hip/hip_runtime.h>

#define B 256
#define K 32
#define M 64
#define MN 256
#define E 128
#define H 128
#define Q 128
#define NSLOT 258   // NNODES+2
#define CTILE 32

__device__ __forceinline__ float lrelu(float x){ return x >= 0.f ? x : 0.01f*x; }

// K1: init = lrelu(hidden_W @ ent[start] + hb); wninit = pass_W[:, :H] @ init
__global__ void k_init(const int* __restrict__ start_ent,
                       const float* __restrict__ ent_emb,
                       const float* __restrict__ hW, const float* __restrict__ hb,
                       const float* __restrict__ passW,
                       float* __restrict__ init_out, float* __restrict__ wninit_out){
    int b = blockIdx.x, t = threadIdx.x;   // 128 threads
    __shared__ float e[E];
    __shared__ float si[H];
    e[t] = ent_emb[(long)start_ent[b]*E + t];
    __syncthreads();
    float acc = hb[t];
    #pragma unroll 8
    for (int j=0;j<E;j++) acc += hW[t*E+j]*e[j];
    float v = lrelu(acc);
    si[t] = v;
    init_out[b*H+t] = v;
    __syncthreads();
    float acc2 = 0.f;
    #pragma unroll 8
    for (int j=0;j<H;j++) acc2 += passW[t*(H+E)+j]*si[j];
    wninit_out[b*H+t] = acc2;
}

// K2: per-b slot map: -2 = zero, -1 = init, k>=0 = upd[b,k]
__global__ void k_map(const int* __restrict__ node_pos, int* __restrict__ map){
    int b = blockIdx.x, t = threadIdx.x;   // 256 threads
    for (int i=t;i<NSLOT;i+=256) map[b*NSLOT+i] = -2;
    __syncthreads();
    if (t==0) map[b*NSLOT+0] = -1;
    __syncthreads();
    if (t<K) map[b*NSLOT + node_pos[b*K+t]] = t;
}

// K3: agg + upd; one block per (b,k), 128 threads
__global__ void k_upd(const int* __restrict__ aims, const int* __restrict__ nbr_nodes,
                      const int* __restrict__ nbr_rels, const int* __restrict__ nbr_num,
                      const float* __restrict__ ent_emb, const float* __restrict__ rel_emb,
                      const float* __restrict__ hW, const float* __restrict__ hb,
                      const float* __restrict__ passW, const float* __restrict__ passb,
                      const float* __restrict__ wninit,
                      float* __restrict__ upd){
    int bk = blockIdx.x;          // b*K + k
    int b = bk / K;
    int t = threadIdx.x;          // 0..127
    int num = nbr_num[bk];
    __shared__ float relsum[E];
    __shared__ float ae[E];
    __shared__ int sc0;
    float rs = 0.f;
    const int* nr = nbr_rels + (long)bk*M;
    for (int m=0;m<num;m++) rs += rel_emb[(long)nr[m]*E + t];
    relsum[t] = rs;
    ae[t] = ent_emb[(long)aims[bk]*E + t];
    if (t < 64) {   // whole wave 0
        bool flag = (t < num) && (nbr_nodes[(long)bk*M + t] == 0);
        unsigned long long mask = __ballot(flag);
        if (t==0) sc0 = (int)__popcll(mask);
    }
    __syncthreads();
    int c0 = sc0;
    float denom = (float)(num > 0 ? num : 1);
    float val = (float)c0 * wninit[b*H+t] + (float)num * passb[t];
    const float* pw = passW + t*(H+E) + H;
    #pragma unroll 8
    for (int j=0;j<E;j++) val += pw[j]*relsum[j];
    float agg = val / denom;
    float acc = hb[t] + agg;
    #pragma unroll 8
    for (int j=0;j<E;j++) acc += hW[t*E+j]*ae[j];
    upd[(long)bk*H + t] = lrelu(acc);
}

// K4: state + thresh; one block per b, 128 threads
__global__ void k_state(const int* __restrict__ currents, const int* __restrict__ map,
                        const float* __restrict__ init, const float* __restrict__ upd,
                        const float* __restrict__ query,
                        const float* __restrict__ nW, const float* __restrict__ nb,
                        const float* __restrict__ gW, const float* __restrict__ gb,
                        float* __restrict__ state, float* __restrict__ out){
    int b = blockIdx.x, t = threadIdx.x;  // 128
    __shared__ float cc[H+Q];
    __shared__ float wsum[2];
    int mv = map[b*NSLOT + currents[b]];
    float cv = 0.f;
    if (mv == -1) cv = init[b*H+t];
    else if (mv >= 0) cv = upd[((long)b*K+mv)*H + t];
    cc[t] = cv;
    cc[H+t] = query[b*Q+t];
    __syncthreads();
    float acc = nb[t];
    #pragma unroll 8
    for (int j=0;j<H+Q;j++) acc += nW[t*(H+Q)+j]*cc[j];
    state[b*H+t] = lrelu(acc);
    // thresh = gate_W . cur_cat + gate_b
    float tv = gW[t]*cc[t] + gW[H+t]*cc[H+t];
    for (int off=32; off>0; off>>=1) tv += __shfl_down(tv, off);
    if ((t&63)==0) wsum[t>>6] = tv;
    __syncthreads();
    if (t==0) out[b*(MN+1) + MN] = wsum[0] + wsum[1] + gb[0];
}

// K5: candidate linear + lrelu + fused score; block = (b, 32-cand tile), 256 threads
__global__ void k_cand(const int* __restrict__ cnodes, const int* __restrict__ cents,
                       const int* __restrict__ crels, const int* __restrict__ cmask,
                       const int* __restrict__ map,
                       const float* __restrict__ init, const float* __restrict__ upd,
                       const float* __restrict__ ent_emb, const float* __restrict__ rel_emb,
                       const float* __restrict__ cW, const float* __restrict__ cb,
                       const float* __restrict__ state,
                       float* __restrict__ out){
    int blk = blockIdx.x;
    int b  = blk >> 3;            // MN/CTILE = 8 tiles per b
    int c0 = (blk & 7) * CTILE;
    int t  = threadIdx.x;         // 0..255
    __shared__ float X[CTILE][385];
    __shared__ float sscore[CTILE];
    if (t < CTILE) sscore[t] = 0.f;
    // stage X = [cnode | ent | rel] per candidate
    for (int c=0;c<CTILE;c++){
        int row = b*MN + c0 + c;
        if (t < 128) {
            int cn = cnodes[row];
            int mv = map[b*NSLOT + cn];
            float v = 0.f;
            if (mv == -1) v = init[b*H+t];
            else if (mv >= 0) v = upd[((long)b*K+mv)*H + t];
            X[c][t] = v;
        } else {
            int tt = t - 128;
            X[c][128 + tt] = ent_emb[(long)cents[row]*E + tt];
        }
    }
    for (int c=0;c<CTILE;c++){
        int row = b*MN + c0 + c;
        if (t < 128) X[c][256 + t] = rel_emb[(long)crels[row]*E + t];
    }
    __syncthreads();
    int h = t & 127;
    int g = t >> 7;               // which 16-cand half
    float acc[16];
    float cbh = cb[h];
    #pragma unroll
    for (int i=0;i<16;i++) acc[i] = cbh;
    const float* w = cW + (long)h*384;
    for (int j=0;j<384;j++){
        float wv = w[j];
        #pragma unroll
        for (int i=0;i<16;i++) acc[i] += wv * X[g*16+i][j];
    }
    float sh = state[b*H + h];
    int lane = t & 63;
    #pragma unroll
    for (int i=0;i<16;i++){
        float v = sh * lrelu(acc[i]);
        for (int off=32; off>0; off>>=1) v += __shfl_down(v, off);
        if (lane == 0) atomicAdd(&sscore[g*16+i], v);
    }
    __syncthreads();
    if (t < CTILE) {
        int row = b*MN + c0 + t;
        float s = sscore[t] * 0.08838834764831845f;  // 1/sqrt(128)
        out[b*(MN+1) + c0 + t] = cmask[row] ? s : -100000.0f;
    }
}

extern "C" void kernel_launch(void* const* d_in, const int* in_sizes, int n_in,
                              void* d_out, int out_size, void* d_ws, size_t ws_size,
                              hipStream_t stream){
    (void)in_sizes; (void)n_in; (void)out_size; (void)ws_size;
    const int* start_entities      = (const int*)d_in[0];
    const int* aims                = (const int*)d_in[1];
    const int* node_pos            = (const int*)d_in[2];
    const int* neighbor_nodes      = (const int*)d_in[3];
    const int* neighbor_relations  = (const int*)d_in[4];
    const int* neighbors_num       = (const int*)d_in[5];
    const int* currents            = (const int*)d_in[6];
    const int* candidate_nodes     = (const int*)d_in[7];
    const int* candidate_entities  = (const int*)d_in[8];
    const int* candidate_relations = (const int*)d_in[9];
    const int* candidate_masks     = (const int*)d_in[10];
    const float* entity_emb   = (const float*)d_in[11];
    const float* relation_emb = (const float*)d_in[12];
    const float* hidden_W     = (const float*)d_in[13];
    const float* hidden_b     = (const float*)d_in[14];
    const float* pass_W       = (const float*)d_in[15];
    const float* pass_b       = (const float*)d_in[16];
    const float* nexthop_W    = (const float*)d_in[17];
    const float* nexthop_b    = (const float*)d_in[18];
    const float* candidate_W  = (const float*)d_in[19];
    const float* candidate_b  = (const float*)d_in[20];
    const float* gate_W       = (const float*)d_in[21];
    const float* gate_b       = (const float*)d_in[22];
    const float* query        = (const float*)d_in[23];
    float* out = (float*)d_out;

    float* ws     = (float*)d_ws;
    float* init   = ws;                    // B*H
    float* wninit = init + B*H;            // B*H
    float* upd    = wninit + B*H;          // B*K*H
    float* state  = upd + (long)B*K*H;     // B*H
    int*   map    = (int*)(state + B*H);   // B*NSLOT

    k_init<<<B, 128, 0, stream>>>(start_entities, entity_emb, hidden_W, hidden_b,
                                  pass_W, init, wninit);
    k_map<<<B, 256, 0, stream>>>(node_pos, map);
    k_upd<<<B*K, 128, 0, stream>>>(aims, neighbor_nodes, neighbor_relations, neighbors_num,
                                   entity_emb, relation_emb, hidden_W, hidden_b,
                                   pass_W, pass_b, wninit, upd);
    k_state<<<B, 128, 0, stream>>>(currents, map, init, upd, query,
                                   nexthop_W, nexthop_b, gate_W, gate_b, state, out);
    k_cand<<<B*(MN/CTILE), 256, 0, stream>>>(candidate_nodes, candidate_entities,
                                             candidate_relations, candidate_masks,
                                             map, init, upd, entity_emb, relation_emb,
                                             candidate_W, candidate_b, state, out);
}

// Round 3
// 224.000 us; speedup vs baseline: 1.5029x; 1.5029x over previous
//
#include <hip/hip_runtime.h>

#define B 256
#define K 32
#define M 64
#define MN 256
#define E 128
#define H 128
#define Q 128
#define NSLOT 258   // NNODES+2
#define CTILE 32
#define XPAD 392    // 384 + 8 bf16 pad (16B) -> 2-way LDS aliasing only (free)

typedef __attribute__((ext_vector_type(8))) short short8;
typedef __attribute__((ext_vector_type(4))) float f32x4;

__device__ __forceinline__ float lrelu(float x){ return x >= 0.f ? x : 0.01f*x; }

// fp32 -> bf16 RTNE
__device__ __forceinline__ unsigned short f2bf(float f){
    unsigned int u = __float_as_uint(f);
    unsigned int r = u + 0x7FFFu + ((u >> 16) & 1u);
    return (unsigned short)(r >> 16);
}

// K0: convert candidate_W (128x384 fp32) to bf16 once
__global__ void k_cvtw(const float* __restrict__ w, unsigned short* __restrict__ o, int n){
    int i = blockIdx.x*256 + threadIdx.x;
    if (i < n) o[i] = f2bf(w[i]);
}

// K1: init = lrelu(hidden_W @ ent[start] + hb); wninit = pass_W[:, :H] @ init
__global__ void k_init(const int* __restrict__ start_ent,
                       const float* __restrict__ ent_emb,
                       const float* __restrict__ hW, const float* __restrict__ hb,
                       const float* __restrict__ passW,
                       float* __restrict__ init_out, float* __restrict__ wninit_out){
    int b = blockIdx.x, t = threadIdx.x;   // 128 threads
    __shared__ float e[E];
    __shared__ float si[H];
    e[t] = ent_emb[(long)start_ent[b]*E + t];
    __syncthreads();
    float acc = hb[t];
    #pragma unroll 8
    for (int j=0;j<E;j++) acc += hW[t*E+j]*e[j];
    float v = lrelu(acc);
    si[t] = v;
    init_out[b*H+t] = v;
    __syncthreads();
    float acc2 = 0.f;
    #pragma unroll 8
    for (int j=0;j<H;j++) acc2 += passW[t*(H+E)+j]*si[j];
    wninit_out[b*H+t] = acc2;
}

// K2: per-b slot map: -2 = zero, -1 = init, k>=0 = upd[b,k]
__global__ void k_map(const int* __restrict__ node_pos, int* __restrict__ map){
    int b = blockIdx.x, t = threadIdx.x;   // 256 threads
    for (int i=t;i<NSLOT;i+=256) map[b*NSLOT+i] = -2;
    __syncthreads();
    if (t==0) map[b*NSLOT+0] = -1;
    __syncthreads();
    if (t<K) map[b*NSLOT + node_pos[b*K+t]] = t;
}

// K3: agg + upd; one block per (b,k), 256 threads (2-way split of m-loop and matvecs)
__global__ void k_upd(const int* __restrict__ aims, const int* __restrict__ nbr_nodes,
                      const int* __restrict__ nbr_rels, const int* __restrict__ nbr_num,
                      const float* __restrict__ ent_emb, const float* __restrict__ rel_emb,
                      const float* __restrict__ hW, const float* __restrict__ hb,
                      const float* __restrict__ passW, const float* __restrict__ passb,
                      const float* __restrict__ wninit,
                      float* __restrict__ upd){
    int bk = blockIdx.x;          // b*K + k
    int b = bk / K;
    int t = threadIdx.x;          // 0..255
    int g = t >> 7, d = t & 127;
    int num = nbr_num[bk];
    __shared__ float rp[2][128];
    __shared__ float rsum[128];
    __shared__ float ae[128];
    __shared__ float pp[2][128];
    __shared__ int sc0;
    const int* nr = nbr_rels + (long)bk*M;
    float rs = 0.f;
    for (int m=g; m<num; m+=2) rs += rel_emb[(long)nr[m]*E + d];
    rp[g][d] = rs;
    if (t < 128) ae[d] = ent_emb[(long)aims[bk]*E + d];
    if (t < 64) {   // whole wave 0
        bool flag = (t < num) && (nbr_nodes[(long)bk*M + t] == 0);
        unsigned long long mask = __ballot(flag);
        if (t==0) sc0 = (int)__popcll(mask);
    }
    __syncthreads();
    if (t < 128) rsum[d] = rp[0][d] + rp[1][d];
    __syncthreads();
    float denom = (float)(num > 0 ? num : 1);
    float ppass = 0.f, phid = 0.f;
    const float* pw = passW + d*(H+E) + H + g*64;
    const float* hw = hW + d*E + g*64;
    const float* rsh = rsum + g*64;
    const float* aeh = ae + g*64;
    #pragma unroll 8
    for (int j=0;j<64;j++){ ppass += pw[j]*rsh[j]; phid += hw[j]*aeh[j]; }
    pp[g][d] = ppass/denom + phid;
    __syncthreads();
    if (t < 128) {
        float v = hb[d] + ((float)sc0*wninit[b*H+d] + (float)num*passb[d])/denom
                + pp[0][d] + pp[1][d];
        upd[(long)bk*H + d] = lrelu(v);
    }
}

// K4: state + thresh; one block per b, 128 threads
__global__ void k_state(const int* __restrict__ currents, const int* __restrict__ map,
                        const float* __restrict__ init, const float* __restrict__ upd,
                        const float* __restrict__ query,
                        const float* __restrict__ nW, const float* __restrict__ nb,
                        const float* __restrict__ gW, const float* __restrict__ gb,
                        float* __restrict__ state, float* __restrict__ out){
    int b = blockIdx.x, t = threadIdx.x;  // 128
    __shared__ float cc[H+Q];
    __shared__ float wsum[2];
    int mv = map[b*NSLOT + currents[b]];
    float cv = 0.f;
    if (mv == -1) cv = init[b*H+t];
    else if (mv >= 0) cv = upd[((long)b*K+mv)*H + t];
    cc[t] = cv;
    cc[H+t] = query[b*Q+t];
    __syncthreads();
    float acc = nb[t];
    #pragma unroll 8
    for (int j=0;j<H+Q;j++) acc += nW[t*(H+Q)+j]*cc[j];
    state[b*H+t] = lrelu(acc);
    float tv = gW[t]*cc[t] + gW[H+t]*cc[H+t];
    for (int off=32; off>0; off>>=1) tv += __shfl_down(tv, off);
    if ((t&63)==0) wsum[t>>6] = tv;
    __syncthreads();
    if (t==0) out[b*(MN+1) + MN] = wsum[0] + wsum[1] + gb[0];
}

// K5: candidate linear via bf16 MFMA + fused lrelu*state score
// block = (b, 32-cand tile), 256 threads = 4 waves; wave w owns h-cols [w*32, w*32+32)
__global__ void k_cand(const int* __restrict__ cnodes, const int* __restrict__ cents,
                       const int* __restrict__ crels, const int* __restrict__ cmask,
                       const int* __restrict__ map,
                       const float* __restrict__ init, const float* __restrict__ upd,
                       const float* __restrict__ ent_emb, const float* __restrict__ rel_emb,
                       const unsigned short* __restrict__ cWb, const float* __restrict__ cb,
                       const float* __restrict__ state,
                       float* __restrict__ out){
    int blk = blockIdx.x;
    int b  = blk >> 3;            // MN/CTILE = 8 tiles per b
    int c0 = (blk & 7) * CTILE;
    int t  = threadIdx.x;         // 0..255

    __shared__ __align__(16) unsigned short Xb[CTILE][XPAD];
    __shared__ float sscore[CTILE];

    if (t < CTILE) sscore[t] = 0.f;

    // ---- stage X = [cnode | ent | rel] as bf16, two candidates per pass ----
    int half = t >> 7;            // 0 or 1
    int d = t & 127;
    for (int cc = 0; cc < CTILE; cc += 2) {
        int c = cc + half;
        int row = b*MN + c0 + c;
        int cn = cnodes[row];
        int mv = map[b*NSLOT + cn];
        float nv = 0.f;
        if (mv == -1) nv = init[b*H+d];
        else if (mv >= 0) nv = upd[((long)b*K+mv)*H + d];
        float ev = ent_emb[(long)cents[row]*E + d];
        float rv = rel_emb[(long)crels[row]*E + d];
        Xb[c][d]       = f2bf(nv);
        Xb[c][128 + d] = f2bf(ev);
        Xb[c][256 + d] = f2bf(rv);
    }
    __syncthreads();

    // ---- MFMA: C[32 cands][128 h] = X(32x384) @ W^T(384x128), bf16 in / f32 acc ----
    int w    = t >> 6;            // wave id 0..3
    int lane = t & 63;
    int l16  = lane & 15;
    int lhi  = lane >> 4;         // 0..3
    f32x4 acc[2][2];
    #pragma unroll
    for (int rt=0;rt<2;rt++)
        #pragma unroll
        for (int ct=0;ct<2;ct++)
            acc[rt][ct] = (f32x4){0.f,0.f,0.f,0.f};

    #pragma unroll 4
    for (int ks = 0; ks < 12; ks++) {
        int kof = ks*32 + lhi*8;
        // A frags: rows rt*16 + l16, k = kof..kof+7 (16B aligned: XPAD*2=784%16==0, kof*2%16==0)
        short8 a0 = *(const short8*)&Xb[l16][kof];
        short8 a1 = *(const short8*)&Xb[16 + l16][kof];
        // B frags: col h = w*32 + ct*16 + l16, same k range, from bf16 W copy
        short8 b0 = *(const short8*)&cWb[(long)(w*32 + l16)*384 + kof];
        short8 b1 = *(const short8*)&cWb[(long)(w*32 + 16 + l16)*384 + kof];
        acc[0][0] = __builtin_amdgcn_mfma_f32_16x16x32_bf16(a0, b0, acc[0][0], 0, 0, 0);
        acc[0][1] = __builtin_amdgcn_mfma_f32_16x16x32_bf16(a0, b1, acc[0][1], 0, 0, 0);
        acc[1][0] = __builtin_amdgcn_mfma_f32_16x16x32_bf16(a1, b0, acc[1][0], 0, 0, 0);
        acc[1][1] = __builtin_amdgcn_mfma_f32_16x16x32_bf16(a1, b1, acc[1][1], 0, 0, 0);
    }

    // ---- epilogue: cand = lrelu(acc + cb[h]); score partial = cand * state[h]; reduce over h ----
    // D layout: col h = base + l16, row (cand) = rt*16 + 4*lhi + i
    float s0 = state[b*H + w*32 + l16];
    float s1 = state[b*H + w*32 + 16 + l16];
    float cb0 = cb[w*32 + l16];
    float cb1 = cb[w*32 + 16 + l16];
    #pragma unroll
    for (int rt=0; rt<2; rt++) {
        float ps[4];
        #pragma unroll
        for (int i=0;i<4;i++)
            ps[i] = lrelu(acc[rt][0][i] + cb0)*s0 + lrelu(acc[rt][1][i] + cb1)*s1;
        // reduce across the 16-lane col group (h dim)
        #pragma unroll
        for (int msk=1; msk<16; msk<<=1) {
            #pragma unroll
            for (int i=0;i<4;i++) ps[i] += __shfl_xor(ps[i], msk);
        }
        if (l16 == 0) {
            #pragma unroll
            for (int i=0;i<4;i++)
                atomicAdd(&sscore[rt*16 + 4*lhi + i], ps[i]);
        }
    }
    __syncthreads();

    if (t < CTILE) {
        int row = b*MN + c0 + t;
        float s = sscore[t] * 0.08838834764831845f;  // 1/sqrt(128)
        out[b*(MN+1) + c0 + t] = cmask[row] ? s : -100000.0f;
    }
}

extern "C" void kernel_launch(void* const* d_in, const int* in_sizes, int n_in,
                              void* d_out, int out_size, void* d_ws, size_t ws_size,
                              hipStream_t stream){
    (void)in_sizes; (void)n_in; (void)out_size; (void)ws_size;
    const int* start_entities      = (const int*)d_in[0];
    const int* aims                = (const int*)d_in[1];
    const int* node_pos            = (const int*)d_in[2];
    const int* neighbor_nodes      = (const int*)d_in[3];
    const int* neighbor_relations  = (const int*)d_in[4];
    const int* neighbors_num       = (const int*)d_in[5];
    const int* currents            = (const int*)d_in[6];
    const int* candidate_nodes     = (const int*)d_in[7];
    const int* candidate_entities  = (const int*)d_in[8];
    const int* candidate_relations = (const int*)d_in[9];
    const int* candidate_masks     = (const int*)d_in[10];
    const float* entity_emb   = (const float*)d_in[11];
    const float* relation_emb = (const float*)d_in[12];
    const float* hidden_W     = (const float*)d_in[13];
    const float* hidden_b     = (const float*)d_in[14];
    const float* pass_W       = (const float*)d_in[15];
    const float* pass_b       = (const float*)d_in[16];
    const float* nexthop_W    = (const float*)d_in[17];
    const float* nexthop_b    = (const float*)d_in[18];
    const float* candidate_W  = (const float*)d_in[19];
    const float* candidate_b  = (const float*)d_in[20];
    const float* gate_W       = (const float*)d_in[21];
    const float* gate_b       = (const float*)d_in[22];
    const float* query        = (const float*)d_in[23];
    float* out = (float*)d_out;

    float* ws     = (float*)d_ws;
    float* init   = ws;                    // B*H
    float* wninit = init + B*H;            // B*H
    float* upd    = wninit + B*H;          // B*K*H
    float* state  = upd + (long)B*K*H;     // B*H
    int*   map    = (int*)(state + B*H);   // B*NSLOT
    unsigned short* cWb = (unsigned short*)(map + B*NSLOT);  // H*(H+2E) bf16

    k_cvtw<<<(H*384 + 255)/256, 256, 0, stream>>>(candidate_W, cWb, H*384);
    k_init<<<B, 128, 0, stream>>>(start_entities, entity_emb, hidden_W, hidden_b,
                                  pass_W, init, wninit);
    k_map<<<B, 256, 0, stream>>>(node_pos, map);
    k_upd<<<B*K, 256, 0, stream>>>(aims, neighbor_nodes, neighbor_relations, neighbors_num,
                                   entity_emb, relation_emb, hidden_W, hidden_b,
                                   pass_W, pass_b, wninit, upd);
    k_state<<<B, 128, 0, stream>>>(currents, map, init, upd, query,
                                   nexthop_W, nexthop_b, gate_W, gate_b, state, out);
    k_cand<<<B*(MN/CTILE), 256, 0, stream>>>(candidate_nodes, candidate_entities,
                                             candidate_relations, candidate_masks,
                                             map, init, upd, entity_emb, relation_emb,
                                             cWb, candidate_b, state, out);
}

// Round 4
// 96.410 us; speedup vs baseline: 3.4918x; 2.3234x over previous
//
#include <hip/hip_runtime.h>

#define B 256
#define K 32
#define M 64
#define MN 256
#define E 128
#define H 128
#define Q 128
#define NSLOT 258   // NNODES+2
#define CTILE 32
#define XPAD 392    // 384 + 8 bf16 pad

typedef __attribute__((ext_vector_type(8))) short short8;
typedef __attribute__((ext_vector_type(4))) float f32x4;

__device__ __forceinline__ float lrelu(float x){ return x >= 0.f ? x : 0.01f*x; }

// fp32 -> bf16 RTNE
__device__ __forceinline__ unsigned short f2bf(float f){
    unsigned int u = __float_as_uint(f);
    unsigned int r = u + 0x7FFFu + ((u >> 16) & 1u);
    return (unsigned short)(r >> 16);
}

// K0a: convert candidate_W (128x384 fp32) to bf16
__global__ void k_cvtw(const float* __restrict__ w, unsigned short* __restrict__ o, int n){
    int i = blockIdx.x*256 + threadIdx.x;
    if (i < n) o[i] = f2bf(w[i]);
}

// K0b: build Wcat (128x256 bf16) = [pass_W[:,H:H+128] | hidden_W]
__global__ void k_cvtw2(const float* __restrict__ passW, const float* __restrict__ hW,
                        unsigned short* __restrict__ o){
    int i = blockIdx.x*256 + threadIdx.x;   // 0..32767
    int h = i >> 8, j = i & 255;
    float v = (j < 128) ? passW[h*(H+E) + H + j] : hW[h*E + (j-128)];
    o[i] = f2bf(v);
}

// K1: init = lrelu(hidden_W @ ent[start] + hb); wninit = pass_W[:, :H] @ init
__global__ void k_init(const int* __restrict__ start_ent,
                       const float* __restrict__ ent_emb,
                       const float* __restrict__ hW, const float* __restrict__ hb,
                       const float* __restrict__ passW,
                       float* __restrict__ init_out, float* __restrict__ wninit_out){
    int b = blockIdx.x, t = threadIdx.x;   // 128 threads
    __shared__ float e[E];
    __shared__ float si[H];
    e[t] = ent_emb[(long)start_ent[b]*E + t];
    __syncthreads();
    float acc = hb[t];
    #pragma unroll 8
    for (int j=0;j<E;j++) acc += hW[t*E+j]*e[j];
    float v = lrelu(acc);
    si[t] = v;
    init_out[b*H+t] = v;
    __syncthreads();
    float acc2 = 0.f;
    #pragma unroll 8
    for (int j=0;j<H;j++) acc2 += passW[t*(H+E)+j]*si[j];
    wninit_out[b*H+t] = acc2;
}

// K2: per-b slot map: -2 = zero, -1 = init, k>=0 = upd[b,k]
__global__ void k_map(const int* __restrict__ node_pos, int* __restrict__ map){
    int b = blockIdx.x, t = threadIdx.x;   // 256 threads
    for (int i=t;i<NSLOT;i+=256) map[b*NSLOT+i] = -2;
    __syncthreads();
    if (t==0) map[b*NSLOT+0] = -1;
    __syncthreads();
    if (t<K) map[b*NSLOT + node_pos[b*K+t]] = t;
}

// K3a: per (b,k): parallel rel-row gather-sum, c0 count, emit bf16 X row + alpha/beta
__global__ void k_gather(const int* __restrict__ aims, const int* __restrict__ nbr_nodes,
                         const int* __restrict__ nbr_rels, const int* __restrict__ nbr_num,
                         const float* __restrict__ ent_emb, const float* __restrict__ rel_emb,
                         unsigned short* __restrict__ Xg,   // (B*K) x 256 bf16
                         float* __restrict__ ab){           // (B*K) x 2
    int bk = blockIdx.x;
    int t = threadIdx.x;          // 0..255
    int num = nbr_num[bk];
    __shared__ int sidx[M];
    __shared__ int sc0;
    __shared__ float red[8][128];
    if (t < 64) sidx[t] = nbr_rels[(long)bk*M + t];
    if (t >= 64 && t < 128) {     // exactly wave 1
        int m = t - 64;
        bool flag = (m < num) && (nbr_nodes[(long)bk*M + m] == 0);
        unsigned long long mask = __ballot(flag);
        if (m == 0) sc0 = (int)__popcll(mask);
    }
    if (t >= 128) {               // waves 2,3: aim entity row -> X[128..255]
        int d = t - 128;
        Xg[(long)bk*256 + 128 + d] = f2bf(ent_emb[(long)aims[bk]*E + d]);
    }
    __syncthreads();
    // m-parallel gather: 8 rows in flight, each wave reads 2 contiguous 512B rows
    int mg = t >> 5, q = t & 31;
    float4 acc = {0.f,0.f,0.f,0.f};
    for (int m = mg; m < num; m += 8) {
        const float4 v = *(const float4*)&rel_emb[(long)sidx[m]*E + q*4];
        acc.x += v.x; acc.y += v.y; acc.z += v.z; acc.w += v.w;
    }
    red[mg][q*4+0] = acc.x; red[mg][q*4+1] = acc.y;
    red[mg][q*4+2] = acc.z; red[mg][q*4+3] = acc.w;
    __syncthreads();
    float denom = (float)(num > 0 ? num : 1);
    if (t < 128) {
        float s = 0.f;
        #pragma unroll
        for (int g=0; g<8; g++) s += red[g][t];
        Xg[(long)bk*256 + t] = f2bf(s / denom);
    }
    if (t == 0) {
        ab[bk*2+0] = (float)sc0 / denom;
        ab[bk*2+1] = (float)num / denom;
    }
}

// K3b: upd = lrelu(hb + alpha*wninit[b] + beta*passb + X @ Wcat^T) via bf16 MFMA
// block b (=batch b), rows bk = b*32..b*32+31; 256 threads = 4 waves, wave w owns h-cols [w*32,w*32+32)
__global__ void k_updg(const unsigned short* __restrict__ Xg, const float* __restrict__ ab,
                       const unsigned short* __restrict__ Wcat,
                       const float* __restrict__ hb_, const float* __restrict__ passb,
                       const float* __restrict__ wninit,
                       float* __restrict__ upd){
    int b = blockIdx.x;
    int t = threadIdx.x;          // 0..255
    __shared__ __align__(16) unsigned short Xs[32][264];
    __shared__ float wni[128];
    __shared__ float sab[64];
    #pragma unroll
    for (int it = 0; it < 4; it++) {
        int idx = it*256 + t;     // 0..1023 short8 chunks
        int r = idx >> 5;
        int cc = (idx & 31) * 8;
        *(short8*)&Xs[r][cc] = *(const short8*)&Xg[((long)b*32 + r)*256 + cc];
    }
    if (t < 128) wni[t] = wninit[b*128 + t];
    else if (t < 192) sab[t-128] = ab[b*64 + (t-128)];
    __syncthreads();

    int w    = t >> 6;
    int lane = t & 63;
    int l16  = lane & 15;
    int lhi  = lane >> 4;
    int hbase = w*32;
    f32x4 acc[2][2];
    #pragma unroll
    for (int rt=0;rt<2;rt++)
        #pragma unroll
        for (int ct=0;ct<2;ct++)
            acc[rt][ct] = (f32x4){0.f,0.f,0.f,0.f};

    #pragma unroll
    for (int ks = 0; ks < 8; ks++) {
        int kof = ks*32 + lhi*8;
        short8 a0 = *(const short8*)&Xs[l16][kof];
        short8 a1 = *(const short8*)&Xs[16 + l16][kof];
        short8 b0 = *(const short8*)&Wcat[(long)(hbase + l16)*256 + kof];
        short8 b1 = *(const short8*)&Wcat[(long)(hbase + 16 + l16)*256 + kof];
        acc[0][0] = __builtin_amdgcn_mfma_f32_16x16x32_bf16(a0, b0, acc[0][0], 0, 0, 0);
        acc[0][1] = __builtin_amdgcn_mfma_f32_16x16x32_bf16(a0, b1, acc[0][1], 0, 0, 0);
        acc[1][0] = __builtin_amdgcn_mfma_f32_16x16x32_bf16(a1, b0, acc[1][0], 0, 0, 0);
        acc[1][1] = __builtin_amdgcn_mfma_f32_16x16x32_bf16(a1, b1, acc[1][1], 0, 0, 0);
    }

    int h0 = hbase + l16, h1 = hbase + 16 + l16;
    float hb0 = hb_[h0], hb1 = hb_[h1];
    float pb0 = passb[h0], pb1 = passb[h1];
    float w0 = wni[h0],  w1 = wni[h1];
    #pragma unroll
    for (int rt=0; rt<2; rt++) {
        #pragma unroll
        for (int i=0;i<4;i++) {
            int r = rt*16 + 4*lhi + i;
            float al = sab[r*2], be = sab[r*2+1];
            upd[((long)b*32 + r)*128 + h0] = lrelu(hb0 + al*w0 + be*pb0 + acc[rt][0][i]);
            upd[((long)b*32 + r)*128 + h1] = lrelu(hb1 + al*w1 + be*pb1 + acc[rt][1][i]);
        }
    }
}

// K4: state + thresh; one block per b, 128 threads
__global__ void k_state(const int* __restrict__ currents, const int* __restrict__ map,
                        const float* __restrict__ init, const float* __restrict__ upd,
                        const float* __restrict__ query,
                        const float* __restrict__ nW, const float* __restrict__ nb,
                        const float* __restrict__ gW, const float* __restrict__ gb,
                        float* __restrict__ state, float* __restrict__ out){
    int b = blockIdx.x, t = threadIdx.x;  // 128
    __shared__ float cc[H+Q];
    __shared__ float wsum[2];
    int mv = map[b*NSLOT + currents[b]];
    float cv = 0.f;
    if (mv == -1) cv = init[b*H+t];
    else if (mv >= 0) cv = upd[((long)b*K+mv)*H + t];
    cc[t] = cv;
    cc[H+t] = query[b*Q+t];
    __syncthreads();
    float acc = nb[t];
    #pragma unroll 8
    for (int j=0;j<H+Q;j++) acc += nW[t*(H+Q)+j]*cc[j];
    state[b*H+t] = lrelu(acc);
    float tv = gW[t]*cc[t] + gW[H+t]*cc[H+t];
    for (int off=32; off>0; off>>=1) tv += __shfl_down(tv, off);
    if ((t&63)==0) wsum[t>>6] = tv;
    __syncthreads();
    if (t==0) out[b*(MN+1) + MN] = wsum[0] + wsum[1] + gb[0];
}

// K5: candidate linear via bf16 MFMA + fused lrelu*state score
__global__ void k_cand(const int* __restrict__ cnodes, const int* __restrict__ cents,
                       const int* __restrict__ crels, const int* __restrict__ cmask,
                       const int* __restrict__ map,
                       const float* __restrict__ init, const float* __restrict__ upd,
                       const float* __restrict__ ent_emb, const float* __restrict__ rel_emb,
                       const unsigned short* __restrict__ cWb, const float* __restrict__ cb,
                       const float* __restrict__ state,
                       float* __restrict__ out){
    int blk = blockIdx.x;
    int b  = blk >> 3;
    int c0 = (blk & 7) * CTILE;
    int t  = threadIdx.x;         // 0..255

    __shared__ __align__(16) unsigned short Xb[CTILE][XPAD];
    __shared__ float sscore[CTILE];

    if (t < CTILE) sscore[t] = 0.f;

    int half = t >> 7;
    int d = t & 127;
    for (int cc = 0; cc < CTILE; cc += 2) {
        int c = cc + half;
        int row = b*MN + c0 + c;
        int cn = cnodes[row];
        int mv = map[b*NSLOT + cn];
        float nv = 0.f;
        if (mv == -1) nv = init[b*H+d];
        else if (mv >= 0) nv = upd[((long)b*K+mv)*H + d];
        float ev = ent_emb[(long)cents[row]*E + d];
        float rv = rel_emb[(long)crels[row]*E + d];
        Xb[c][d]       = f2bf(nv);
        Xb[c][128 + d] = f2bf(ev);
        Xb[c][256 + d] = f2bf(rv);
    }
    __syncthreads();

    int w    = t >> 6;
    int lane = t & 63;
    int l16  = lane & 15;
    int lhi  = lane >> 4;
    f32x4 acc[2][2];
    #pragma unroll
    for (int rt=0;rt<2;rt++)
        #pragma unroll
        for (int ct=0;ct<2;ct++)
            acc[rt][ct] = (f32x4){0.f,0.f,0.f,0.f};

    #pragma unroll 4
    for (int ks = 0; ks < 12; ks++) {
        int kof = ks*32 + lhi*8;
        short8 a0 = *(const short8*)&Xb[l16][kof];
        short8 a1 = *(const short8*)&Xb[16 + l16][kof];
        short8 b0 = *(const short8*)&cWb[(long)(w*32 + l16)*384 + kof];
        short8 b1 = *(const short8*)&cWb[(long)(w*32 + 16 + l16)*384 + kof];
        acc[0][0] = __builtin_amdgcn_mfma_f32_16x16x32_bf16(a0, b0, acc[0][0], 0, 0, 0);
        acc[0][1] = __builtin_amdgcn_mfma_f32_16x16x32_bf16(a0, b1, acc[0][1], 0, 0, 0);
        acc[1][0] = __builtin_amdgcn_mfma_f32_16x16x32_bf16(a1, b0, acc[1][0], 0, 0, 0);
        acc[1][1] = __builtin_amdgcn_mfma_f32_16x16x32_bf16(a1, b1, acc[1][1], 0, 0, 0);
    }

    float s0 = state[b*H + w*32 + l16];
    float s1 = state[b*H + w*32 + 16 + l16];
    float cb0 = cb[w*32 + l16];
    float cb1 = cb[w*32 + 16 + l16];
    #pragma unroll
    for (int rt=0; rt<2; rt++) {
        float ps[4];
        #pragma unroll
        for (int i=0;i<4;i++)
            ps[i] = lrelu(acc[rt][0][i] + cb0)*s0 + lrelu(acc[rt][1][i] + cb1)*s1;
        #pragma unroll
        for (int msk=1; msk<16; msk<<=1) {
            #pragma unroll
            for (int i=0;i<4;i++) ps[i] += __shfl_xor(ps[i], msk);
        }
        if (l16 == 0) {
            #pragma unroll
            for (int i=0;i<4;i++)
                atomicAdd(&sscore[rt*16 + 4*lhi + i], ps[i]);
        }
    }
    __syncthreads();

    if (t < CTILE) {
        int row = b*MN + c0 + t;
        float s = sscore[t] * 0.08838834764831845f;  // 1/sqrt(128)
        out[b*(MN+1) + c0 + t] = cmask[row] ? s : -100000.0f;
    }
}

extern "C" void kernel_launch(void* const* d_in, const int* in_sizes, int n_in,
                              void* d_out, int out_size, void* d_ws, size_t ws_size,
                              hipStream_t stream){
    (void)in_sizes; (void)n_in; (void)out_size; (void)ws_size;
    const int* start_entities      = (const int*)d_in[0];
    const int* aims                = (const int*)d_in[1];
    const int* node_pos            = (const int*)d_in[2];
    const int* neighbor_nodes      = (const int*)d_in[3];
    const int* neighbor_relations  = (const int*)d_in[4];
    const int* neighbors_num      = (const int*)d_in[5];
    const int* currents            = (const int*)d_in[6];
    const int* candidate_nodes     = (const int*)d_in[7];
    const int* candidate_entities  = (const int*)d_in[8];
    const int* candidate_relations = (const int*)d_in[9];
    const int* candidate_masks     = (const int*)d_in[10];
    const float* entity_emb   = (const float*)d_in[11];
    const float* relation_emb = (const float*)d_in[12];
    const float* hidden_W     = (const float*)d_in[13];
    const float* hidden_b     = (const float*)d_in[14];
    const float* pass_W       = (const float*)d_in[15];
    const float* pass_b       = (const float*)d_in[16];
    const float* nexthop_W    = (const float*)d_in[17];
    const float* nexthop_b    = (const float*)d_in[18];
    const float* candidate_W  = (const float*)d_in[19];
    const float* candidate_b  = (const float*)d_in[20];
    const float* gate_W       = (const float*)d_in[21];
    const float* gate_b       = (const float*)d_in[22];
    const float* query        = (const float*)d_in[23];
    float* out = (float*)d_out;

    float* ws     = (float*)d_ws;
    float* init   = ws;                        // B*H
    float* wninit = init + B*H;                // B*H
    float* upd    = wninit + B*H;              // B*K*H
    float* state  = upd + (long)B*K*H;         // B*H
    float* ab     = state + B*H;               // B*K*2
    int*   map    = (int*)(ab + B*K*2);        // B*NSLOT
    unsigned short* cWb  = (unsigned short*)(map + B*NSLOT);  // 128*384
    unsigned short* Wcat = cWb + H*384;                        // 128*256
    unsigned short* Xg   = Wcat + H*256;                       // B*K*256

    k_cvtw<<<(H*384 + 255)/256, 256, 0, stream>>>(candidate_W, cWb, H*384);
    k_cvtw2<<<(H*256 + 255)/256, 256, 0, stream>>>(pass_W, hidden_W, Wcat);
    k_init<<<B, 128, 0, stream>>>(start_entities, entity_emb, hidden_W, hidden_b,
                                  pass_W, init, wninit);
    k_map<<<B, 256, 0, stream>>>(node_pos, map);
    k_gather<<<B*K, 256, 0, stream>>>(aims, neighbor_nodes, neighbor_relations, neighbors_num,
                                      entity_emb, relation_emb, Xg, ab);
    k_updg<<<B, 256, 0, stream>>>(Xg, ab, Wcat, hidden_b, pass_b, wninit, upd);
    k_state<<<B, 128, 0, stream>>>(currents, map, init, upd, query,
                                   nexthop_W, nexthop_b, gate_W, gate_b, state, out);
    k_cand<<<B*(MN/CTILE), 256, 0, stream>>>(candidate_nodes, candidate_entities,
                                             candidate_relations, candidate_masks,
                                             map, init, upd, entity_emb, relation_emb,
                                             cWb, candidate_b, state, out);
}

// Round 5
// 85.063 us; speedup vs baseline: 3.9576x; 1.1334x over previous
//
#include <hip/hip_runtime.h>

#define B 256
#define K 32
#define M 64
#define MN 256
#define E 128
#define H 128
#define Q 128
#define NSLOT 258   // NNODES+2
#define CTILE 32
#define XPAD 392    // 384 + 8 bf16 pad

typedef __attribute__((ext_vector_type(8))) short short8;
typedef __attribute__((ext_vector_type(4))) short short4b;
typedef __attribute__((ext_vector_type(4))) float f32x4;

__device__ __forceinline__ float lrelu(float x){ return x >= 0.f ? x : 0.01f*x; }

// fp32 -> bf16 RTNE
__device__ __forceinline__ unsigned short f2bf(float f){
    unsigned int u = __float_as_uint(f);
    unsigned int r = u + 0x7FFFu + ((u >> 16) & 1u);
    return (unsigned short)(r >> 16);
}

__device__ __forceinline__ short4b pack4(float4 v){
    short4b r;
    r.x = (short)f2bf(v.x); r.y = (short)f2bf(v.y);
    r.z = (short)f2bf(v.z); r.w = (short)f2bf(v.w);
    return r;
}

// K0a: convert candidate_W (128x384 fp32) to bf16
__global__ void k_cvtw(const float* __restrict__ w, unsigned short* __restrict__ o, int n){
    int i = blockIdx.x*256 + threadIdx.x;
    if (i < n) o[i] = f2bf(w[i]);
}

// K0b: build Wcat (128x256 bf16) = [pass_W[:,H:H+128] | hidden_W]
__global__ void k_cvtw2(const float* __restrict__ passW, const float* __restrict__ hW,
                        unsigned short* __restrict__ o){
    int i = blockIdx.x*256 + threadIdx.x;   // 0..32767
    int h = i >> 8, j = i & 255;
    float v = (j < 128) ? passW[h*(H+E) + H + j] : hW[h*E + (j-128)];
    o[i] = f2bf(v);
}

// K1: init = lrelu(hidden_W @ ent[start] + hb); wninit = pass_W[:, :H] @ init
__global__ void k_init(const int* __restrict__ start_ent,
                       const float* __restrict__ ent_emb,
                       const float* __restrict__ hW, const float* __restrict__ hb,
                       const float* __restrict__ passW,
                       float* __restrict__ init_out, float* __restrict__ wninit_out){
    int b = blockIdx.x, t = threadIdx.x;   // 128 threads
    __shared__ float e[E];
    __shared__ float si[H];
    e[t] = ent_emb[(long)start_ent[b]*E + t];
    __syncthreads();
    float acc = hb[t];
    #pragma unroll 8
    for (int j=0;j<E;j++) acc += hW[t*E+j]*e[j];
    float v = lrelu(acc);
    si[t] = v;
    init_out[b*H+t] = v;
    __syncthreads();
    float acc2 = 0.f;
    #pragma unroll 8
    for (int j=0;j<H;j++) acc2 += passW[t*(H+E)+j]*si[j];
    wninit_out[b*H+t] = acc2;
}

// K2: per-b slot map: -2 = zero, -1 = init, k>=0 = upd[b,k]
__global__ void k_map(const int* __restrict__ node_pos, int* __restrict__ map){
    int b = blockIdx.x, t = threadIdx.x;   // 256 threads
    for (int i=t;i<NSLOT;i+=256) map[b*NSLOT+i] = -2;
    __syncthreads();
    if (t==0) map[b*NSLOT+0] = -1;
    __syncthreads();
    if (t<K) map[b*NSLOT + node_pos[b*K+t]] = t;
}

// K3a: per (b,k): parallel rel-row gather-sum, c0 count, emit bf16 X row + alpha/beta
__global__ void k_gather(const int* __restrict__ aims, const int* __restrict__ nbr_nodes,
                         const int* __restrict__ nbr_rels, const int* __restrict__ nbr_num,
                         const float* __restrict__ ent_emb, const float* __restrict__ rel_emb,
                         unsigned short* __restrict__ Xg,   // (B*K) x 256 bf16
                         float* __restrict__ ab){           // (B*K) x 2
    int bk = blockIdx.x;
    int t = threadIdx.x;          // 0..255
    int num = nbr_num[bk];
    __shared__ int sidx[M];
    __shared__ int sc0;
    __shared__ float red[8][128];
    if (t < 64) sidx[t] = nbr_rels[(long)bk*M + t];
    if (t >= 64 && t < 128) {     // exactly wave 1
        int m = t - 64;
        bool flag = (m < num) && (nbr_nodes[(long)bk*M + m] == 0);
        unsigned long long mask = __ballot(flag);
        if (m == 0) sc0 = (int)__popcll(mask);
    }
    if (t >= 128) {               // waves 2,3: aim entity row -> X[128..255]
        int d = t - 128;
        Xg[(long)bk*256 + 128 + d] = f2bf(ent_emb[(long)aims[bk]*E + d]);
    }
    __syncthreads();
    int mg = t >> 5, q = t & 31;
    float4 acc = {0.f,0.f,0.f,0.f};
    for (int m = mg; m < num; m += 8) {
        const float4 v = *(const float4*)&rel_emb[(long)sidx[m]*E + q*4];
        acc.x += v.x; acc.y += v.y; acc.z += v.z; acc.w += v.w;
    }
    red[mg][q*4+0] = acc.x; red[mg][q*4+1] = acc.y;
    red[mg][q*4+2] = acc.z; red[mg][q*4+3] = acc.w;
    __syncthreads();
    float denom = (float)(num > 0 ? num : 1);
    if (t < 128) {
        float s = 0.f;
        #pragma unroll
        for (int g=0; g<8; g++) s += red[g][t];
        Xg[(long)bk*256 + t] = f2bf(s / denom);
    }
    if (t == 0) {
        ab[bk*2+0] = (float)sc0 / denom;
        ab[bk*2+1] = (float)num / denom;
    }
}

// K3b: upd = lrelu(hb + alpha*wninit[b] + beta*passb + X @ Wcat^T) via bf16 MFMA
__global__ void k_updg(const unsigned short* __restrict__ Xg, const float* __restrict__ ab,
                       const unsigned short* __restrict__ Wcat,
                       const float* __restrict__ hb_, const float* __restrict__ passb,
                       const float* __restrict__ wninit,
                       float* __restrict__ upd){
    int b = blockIdx.x;
    int t = threadIdx.x;          // 0..255
    __shared__ __align__(16) unsigned short Xs[32][264];
    __shared__ float wni[128];
    __shared__ float sab[64];
    #pragma unroll
    for (int it = 0; it < 4; it++) {
        int idx = it*256 + t;     // 0..1023 short8 chunks
        int r = idx >> 5;
        int cc = (idx & 31) * 8;
        *(short8*)&Xs[r][cc] = *(const short8*)&Xg[((long)b*32 + r)*256 + cc];
    }
    if (t < 128) wni[t] = wninit[b*128 + t];
    else if (t < 192) sab[t-128] = ab[b*64 + (t-128)];
    __syncthreads();

    int w    = t >> 6;
    int lane = t & 63;
    int l16  = lane & 15;
    int lhi  = lane >> 4;
    int hbase = w*32;
    f32x4 acc[2][2];
    #pragma unroll
    for (int rt=0;rt<2;rt++)
        #pragma unroll
        for (int ct=0;ct<2;ct++)
            acc[rt][ct] = (f32x4){0.f,0.f,0.f,0.f};

    #pragma unroll
    for (int ks = 0; ks < 8; ks++) {
        int kof = ks*32 + lhi*8;
        short8 a0 = *(const short8*)&Xs[l16][kof];
        short8 a1 = *(const short8*)&Xs[16 + l16][kof];
        short8 b0 = *(const short8*)&Wcat[(long)(hbase + l16)*256 + kof];
        short8 b1 = *(const short8*)&Wcat[(long)(hbase + 16 + l16)*256 + kof];
        acc[0][0] = __builtin_amdgcn_mfma_f32_16x16x32_bf16(a0, b0, acc[0][0], 0, 0, 0);
        acc[0][1] = __builtin_amdgcn_mfma_f32_16x16x32_bf16(a0, b1, acc[0][1], 0, 0, 0);
        acc[1][0] = __builtin_amdgcn_mfma_f32_16x16x32_bf16(a1, b0, acc[1][0], 0, 0, 0);
        acc[1][1] = __builtin_amdgcn_mfma_f32_16x16x32_bf16(a1, b1, acc[1][1], 0, 0, 0);
    }

    int h0 = hbase + l16, h1 = hbase + 16 + l16;
    float hb0 = hb_[h0], hb1 = hb_[h1];
    float pb0 = passb[h0], pb1 = passb[h1];
    float w0 = wni[h0],  w1 = wni[h1];
    #pragma unroll
    for (int rt=0; rt<2; rt++) {
        #pragma unroll
        for (int i=0;i<4;i++) {
            int r = rt*16 + 4*lhi + i;
            float al = sab[r*2], be = sab[r*2+1];
            upd[((long)b*32 + r)*128 + h0] = lrelu(hb0 + al*w0 + be*pb0 + acc[rt][0][i]);
            upd[((long)b*32 + r)*128 + h1] = lrelu(hb1 + al*w1 + be*pb1 + acc[rt][1][i]);
        }
    }
}

// K4: state + thresh; one block per b, 128 threads
__global__ void k_state(const int* __restrict__ currents, const int* __restrict__ map,
                        const float* __restrict__ init, const float* __restrict__ upd,
                        const float* __restrict__ query,
                        const float* __restrict__ nW, const float* __restrict__ nb,
                        const float* __restrict__ gW, const float* __restrict__ gb,
                        float* __restrict__ state, float* __restrict__ out){
    int b = blockIdx.x, t = threadIdx.x;  // 128
    __shared__ float cc[H+Q];
    __shared__ float wsum[2];
    int mv = map[b*NSLOT + currents[b]];
    float cv = 0.f;
    if (mv == -1) cv = init[b*H+t];
    else if (mv >= 0) cv = upd[((long)b*K+mv)*H + t];
    cc[t] = cv;
    cc[H+t] = query[b*Q+t];
    __syncthreads();
    float acc = nb[t];
    #pragma unroll 8
    for (int j=0;j<H+Q;j++) acc += nW[t*(H+Q)+j]*cc[j];
    state[b*H+t] = lrelu(acc);
    float tv = gW[t]*cc[t] + gW[H+t]*cc[H+t];
    for (int off=32; off>0; off>>=1) tv += __shfl_down(tv, off);
    if ((t&63)==0) wsum[t>>6] = tv;
    __syncthreads();
    if (t==0) out[b*(MN+1) + MN] = wsum[0] + wsum[1] + gb[0];
}

// K5: candidate linear via bf16 MFMA + fused lrelu*state score
// Parallel staging: 8 cands in flight x float4/lane; no LDS atomics in epilogue.
__global__ void k_cand(const int* __restrict__ cnodes, const int* __restrict__ cents,
                       const int* __restrict__ crels, const int* __restrict__ cmask,
                       const int* __restrict__ map,
                       const float* __restrict__ init, const float* __restrict__ upd,
                       const float* __restrict__ ent_emb, const float* __restrict__ rel_emb,
                       const unsigned short* __restrict__ cWb, const float* __restrict__ cb,
                       const float* __restrict__ state,
                       float* __restrict__ out){
    int blk = blockIdx.x;
    int b  = blk >> 3;
    int c0 = (blk & 7) * CTILE;
    int t  = threadIdx.x;         // 0..255

    __shared__ __align__(16) unsigned short Xb[CTILE][XPAD];
    __shared__ float sscore[4][CTILE];
    __shared__ int sce[CTILE], scr[CTILE], smv[CTILE];

    // ---- index resolution: one 32-thread pass (2 dependent loads for map) ----
    if (t < CTILE) {
        int row = b*MN + c0 + t;
        int cn = cnodes[row];
        sce[t] = cents[row];
        scr[t] = crels[row];
        smv[t] = map[b*NSLOT + cn];
    }
    __syncthreads();

    // ---- parallel staging: 8 candidates in flight, float4 per lane, 12 indep loads ----
    {
        int c8 = t >> 5;          // candidate sub-slot 0..7
        int q  = t & 31;          // float4 index within 128 floats
        #pragma unroll
        for (int i = 0; i < 4; i++) {
            int c = i*8 + c8;
            int mv = smv[c];
            float4 nv = {0.f,0.f,0.f,0.f};
            if (mv == -1)      nv = *(const float4*)&init[b*H + q*4];
            else if (mv >= 0)  nv = *(const float4*)&upd[((long)b*K+mv)*H + q*4];
            float4 ev = *(const float4*)&ent_emb[(long)sce[c]*E + q*4];
            float4 rv = *(const float4*)&rel_emb[(long)scr[c]*E + q*4];
            *(short4b*)&Xb[c][q*4]        = pack4(nv);
            *(short4b*)&Xb[c][128 + q*4]  = pack4(ev);
            *(short4b*)&Xb[c][256 + q*4]  = pack4(rv);
        }
    }
    __syncthreads();

    // ---- MFMA: C[32 cands][128 h] = X(32x384) @ W^T(384x128) ----
    int w    = t >> 6;
    int lane = t & 63;
    int l16  = lane & 15;
    int lhi  = lane >> 4;
    f32x4 acc[2][2];
    #pragma unroll
    for (int rt=0;rt<2;rt++)
        #pragma unroll
        for (int ct=0;ct<2;ct++)
            acc[rt][ct] = (f32x4){0.f,0.f,0.f,0.f};

    #pragma unroll 4
    for (int ks = 0; ks < 12; ks++) {
        int kof = ks*32 + lhi*8;
        short8 a0 = *(const short8*)&Xb[l16][kof];
        short8 a1 = *(const short8*)&Xb[16 + l16][kof];
        short8 b0 = *(const short8*)&cWb[(long)(w*32 + l16)*384 + kof];
        short8 b1 = *(const short8*)&cWb[(long)(w*32 + 16 + l16)*384 + kof];
        acc[0][0] = __builtin_amdgcn_mfma_f32_16x16x32_bf16(a0, b0, acc[0][0], 0, 0, 0);
        acc[0][1] = __builtin_amdgcn_mfma_f32_16x16x32_bf16(a0, b1, acc[0][1], 0, 0, 0);
        acc[1][0] = __builtin_amdgcn_mfma_f32_16x16x32_bf16(a1, b0, acc[1][0], 0, 0, 0);
        acc[1][1] = __builtin_amdgcn_mfma_f32_16x16x32_bf16(a1, b1, acc[1][1], 0, 0, 0);
    }

    // ---- epilogue: lrelu + dot(state) partial, reduce over h within wave ----
    float s0 = state[b*H + w*32 + l16];
    float s1 = state[b*H + w*32 + 16 + l16];
    float cb0 = cb[w*32 + l16];
    float cb1 = cb[w*32 + 16 + l16];
    #pragma unroll
    for (int rt=0; rt<2; rt++) {
        float ps[4];
        #pragma unroll
        for (int i=0;i<4;i++)
            ps[i] = lrelu(acc[rt][0][i] + cb0)*s0 + lrelu(acc[rt][1][i] + cb1)*s1;
        #pragma unroll
        for (int msk=1; msk<16; msk<<=1) {
            #pragma unroll
            for (int i=0;i<4;i++) ps[i] += __shfl_xor(ps[i], msk);
        }
        if (l16 == 0) {
            #pragma unroll
            for (int i=0;i<4;i++)
                sscore[w][rt*16 + 4*lhi + i] = ps[i];
        }
    }
    __syncthreads();

    if (t < CTILE) {
        int row = b*MN + c0 + t;
        float s = (sscore[0][t] + sscore[1][t] + sscore[2][t] + sscore[3][t])
                  * 0.08838834764831845f;  // 1/sqrt(128)
        out[b*(MN+1) + c0 + t] = cmask[row] ? s : -100000.0f;
    }
}

extern "C" void kernel_launch(void* const* d_in, const int* in_sizes, int n_in,
                              void* d_out, int out_size, void* d_ws, size_t ws_size,
                              hipStream_t stream){
    (void)in_sizes; (void)n_in; (void)out_size; (void)ws_size;
    const int* start_entities      = (const int*)d_in[0];
    const int* aims                = (const int*)d_in[1];
    const int* node_pos            = (const int*)d_in[2];
    const int* neighbor_nodes      = (const int*)d_in[3];
    const int* neighbor_relations  = (const int*)d_in[4];
    const int* neighbors_num       = (const int*)d_in[5];
    const int* currents            = (const int*)d_in[6];
    const int* candidate_nodes     = (const int*)d_in[7];
    const int* candidate_entities  = (const int*)d_in[8];
    const int* candidate_relations = (const int*)d_in[9];
    const int* candidate_masks     = (const int*)d_in[10];
    const float* entity_emb   = (const float*)d_in[11];
    const float* relation_emb = (const float*)d_in[12];
    const float* hidden_W     = (const float*)d_in[13];
    const float* hidden_b     = (const float*)d_in[14];
    const float* pass_W       = (const float*)d_in[15];
    const float* pass_b       = (const float*)d_in[16];
    const float* nexthop_W    = (const float*)d_in[17];
    const float* nexthop_b    = (const float*)d_in[18];
    const float* candidate_W  = (const float*)d_in[19];
    const float* candidate_b  = (const float*)d_in[20];
    const float* gate_W       = (const float*)d_in[21];
    const float* gate_b       = (const float*)d_in[22];
    const float* query        = (const float*)d_in[23];
    float* out = (float*)d_out;

    float* ws     = (float*)d_ws;
    float* init   = ws;                        // B*H
    float* wninit = init + B*H;                // B*H
    float* upd    = wninit + B*H;              // B*K*H
    float* state  = upd + (long)B*K*H;         // B*H
    float* ab     = state + B*H;               // B*K*2
    int*   map    = (int*)(ab + B*K*2);        // B*NSLOT
    unsigned short* cWb  = (unsigned short*)(map + B*NSLOT);  // 128*384
    unsigned short* Wcat = cWb + H*384;                        // 128*256
    unsigned short* Xg   = Wcat + H*256;                       // B*K*256

    k_cvtw<<<(H*384 + 255)/256, 256, 0, stream>>>(candidate_W, cWb, H*384);
    k_cvtw2<<<(H*256 + 255)/256, 256, 0, stream>>>(pass_W, hidden_W, Wcat);
    k_init<<<B, 128, 0, stream>>>(start_entities, entity_emb, hidden_W, hidden_b,
                                  pass_W, init, wninit);
    k_map<<<B, 256, 0, stream>>>(node_pos, map);
    k_gather<<<B*K, 256, 0, stream>>>(aims, neighbor_nodes, neighbor_relations, neighbors_num,
                                      entity_emb, relation_emb, Xg, ab);
    k_updg<<<B, 256, 0, stream>>>(Xg, ab, Wcat, hidden_b, pass_b, wninit, upd);
    k_state<<<B, 128, 0, stream>>>(currents, map, init, upd, query,
                                   nexthop_W, nexthop_b, gate_W, gate_b, state, out);
    k_cand<<<B*(MN/CTILE), 256, 0, stream>>>(candidate_nodes, candidate_entities,
                                             candidate_relations, candidate_masks,
                                             map, init, upd, entity_emb, relation_emb,
                                             cWb, candidate_b, state, out);
}